// Round 10
// baseline (38.994 us; speedup 1.0000x reference)
//
#include <hip/hip_runtime.h>
#include <math.h>

#define BLKSZ 160
#define NWT   64
#define WTLEN 512
#define FPB   16      // frames per main block
#define SPB   2560    // samples per main block (16*160)

// ReduceWindowRewriter(base_length=16) level sizes for T=960000
#define NB0   60000   // T/16
#define NB1   3750    // NB0/16
#define NB2   235     // ceil(NB1/16)
#define NB2P  240
#define NB3   15      // < 16 -> naive sequential top scan

// f32 increment exactly as the reference: (pitch / 16000) * 512
static __device__ __forceinline__ float inc32_of(float p) {
    return (p / 16000.0f) * 512.0f;
}

// K1: leaf levels. blocks [0,235): per-4096-sample tree -> bs1 (16), bs2 (1).
//     blocks [235,363): wts_eff (rows 0..3 raw, 4..63 tanh).
__global__ __launch_bounds__(256) void k_leaf(
    const float* __restrict__ pitch, const float* __restrict__ wts,
    float* __restrict__ bs1, float* __restrict__ bs2,
    float* __restrict__ wts_eff, int T)
{
    int t = threadIdx.x;
    if (blockIdx.x >= NB2) {                      // wts_eff part
        int i = (blockIdx.x - NB2) * 256 + t;
        if (i < NWT * WTLEN) {
            float v = wts[i];
            if ((i >> 9) >= 4) v = tanhf(v);
            wts_eff[i] = v;
        }
        return;
    }
    __shared__ float b0[256];
    __shared__ float b1[16];
    int blk = blockIdx.x;
    size_t s0 = (size_t)blk * 4096;
    int nsamp = min(4096, T - (int)s0);
    int nb0 = nsamp >> 4;                         // 256 or 96
    if (t < nb0) {                                // bs0: seq 16-chain of incs
        const float4* p4 = (const float4*)(pitch + s0 + (size_t)t * 16);
        float acc = 0.f;
        #pragma unroll
        for (int i = 0; i < 4; ++i) {
            float4 v = p4[i];
            acc = acc + inc32_of(v.x);
            acc = acc + inc32_of(v.y);
            acc = acc + inc32_of(v.z);
            acc = acc + inc32_of(v.w);
        }
        b0[t] = acc;
    }
    __syncthreads();
    int nb1 = nb0 >> 4;                           // 16 or 6
    if (t < nb1) {                                // bs1: seq 16-chain of bs0
        float acc = b0[t * 16];
        for (int j = 1; j < 16; ++j) acc = acc + b0[t * 16 + j];
        b1[t] = acc;
        bs1[blk * 16 + t] = acc;
    }
    __syncthreads();
    if (t == 0) {                                 // bs2: seq chain (pad zeros exact)
        float acc = b1[0];
        for (int j = 1; j < nb1; ++j) acc = acc + b1[j];
        bs2[blk] = acc;
    }
}

// K2: mid levels: bs2 -> bs3 -> S4 -> S3 -> S2  (single small block)
__global__ __launch_bounds__(512) void k_mid(const float* __restrict__ bs1,
                                             const float* __restrict__ bs2,
                                             float* __restrict__ S2)
{
    __shared__ float bs1L[NB1];     // 15000 B
    __shared__ float bs2L[NB2P];    // zero-padded
    __shared__ float bs3L[NB3];
    __shared__ float S4L[NB3];
    __shared__ float S3L[NB2];
    int t = threadIdx.x;
    for (int j = t; j < NB1; j += 512) bs1L[j] = bs1[j];
    if (t < NB2P) bs2L[t] = (t < NB2) ? bs2[t] : 0.f;
    __syncthreads();
    if (t < NB3) {                                // bs3: seq 16-chain of bs2
        float acc = bs2L[t * 16];
        for (int j = 1; j < 16; ++j) acc = acc + bs2L[t * 16 + j];
        bs3L[t] = acc;
    }
    __syncthreads();
    if (t == 0) {                                 // S4: naive seq scan (15 < 16)
        float acc = 0.f;
        for (int i = 0; i < NB3; ++i) { acc = acc + bs3L[i]; S4L[i] = acc; }
    }
    __syncthreads();
    if (t < NB2) {                                // S3 = inner3 + off4
        int r = t >> 4, i = t & 15;
        float acc = bs2L[r * 16];
        for (int k = 1; k <= i; ++k) acc = acc + bs2L[r * 16 + k];
        S3L[t] = r ? (acc + S4L[r - 1]) : acc;
    }
    __syncthreads();
    if (t < NB2) {                                // S2 row r: running prefix + off3
        float off = t ? S3L[t - 1] : 0.f;
        float acc = 0.f;
        int n = min(16, NB1 - t * 16);
        for (int i = 0; i < n; ++i) {
            acc = acc + bs1L[t * 16 + i];
            S2[t * 16 + i] = t ? (acc + off) : acc;
        }
    }
}

// K3: fused softmax -> mixrow (readlane weights) -> prefixes -> lerp -> amp
__global__ __launch_bounds__(512) void k_main(
    const float* __restrict__ pitch, const float* __restrict__ amp,
    const float* __restrict__ att, const float* __restrict__ wts_eff,
    const float* __restrict__ bs1, const float* __restrict__ S2,
    float* __restrict__ out, int frames)
{
    __shared__ float sm[FPB][NWT];          // 4 KB
    __shared__ float mixrow[FPB][WTLEN];    // 32 KB
    __shared__ float pr[SPB];               // 10 KB: inc -> within-16 prefix in place
    __shared__ float roffL[SPB / 16];       // 160
    __shared__ float S2w[11];               // S2[10b-2 .. 10b+8]
    __shared__ float bs1prev;               // bs1[10b-1]

    int tid = threadIdx.x, lane = tid & 63, wv = tid >> 6;
    int b = blockIdx.x;
    int f0 = b * FPB;
    size_t base = (size_t)b * SPB;

    // softmax: 8 waves x 2 frames
    #pragma unroll
    for (int r = 0; r < 2; ++r) {
        int f = f0 + wv * 2 + r;
        float a = att[(size_t)lane * frames + f];
        float m = a;
        #pragma unroll
        for (int off = 32; off; off >>= 1) m = fmaxf(m, __shfl_xor(m, off, 64));
        float e = expf(a - m);
        float s = e;
        #pragma unroll
        for (int off = 32; off; off >>= 1) s += __shfl_xor(s, off, 64);
        sm[wv * 2 + r][lane] = e / s;
    }
    if (tid < 11) {
        int g = 10 * b - 2 + tid;
        S2w[tid] = (g >= 0) ? S2[g] : 0.f;
    }
    if (tid == 11) bs1prev = (b > 0) ? bs1[10 * b - 1] : 0.f;

    // stage incs (keep in regs), before the sync that publishes sm
    float increg[SPB / 512];
    #pragma unroll
    for (int i = 0; i < SPB / 512; ++i) {
        increg[i] = inc32_of(pitch[base + i * 512 + tid]);
        pr[i * 512 + tid] = increg[i];
    }
    __syncthreads();

    // mixrow: weights via v_readlane (VALU), zero LDS traffic in the loop
    {
        float smreg[FPB];                   // smreg[k] = sm[k][lane]
        #pragma unroll
        for (int k = 0; k < FPB; ++k) smreg[k] = sm[k][lane];
        float acc[FPB];
        #pragma unroll
        for (int k = 0; k < FPB; ++k) acc[k] = 0.f;
        #pragma unroll 4
        for (int w = 0; w < NWT; ++w) {
            float v = wts_eff[w * WTLEN + tid];
            #pragma unroll
            for (int k = 0; k < FPB; ++k) {
                float s = __uint_as_float(
                    __builtin_amdgcn_readlane(__float_as_uint(smreg[k]), w));
                acc[k] = acc[k] + s * v;
            }
        }
        #pragma unroll
        for (int k = 0; k < FPB; ++k) mixrow[k][tid] = acc[k];
    }

    // within-16 inclusive prefixes, in place (same chain order as ref level 0)
    if (tid < SPB / 16) {
        int bofs = tid * 16;
        float acc = pr[bofs];
        for (int j = 1; j < 16; ++j) { acc = acc + pr[bofs + j]; pr[bofs + j] = acc; }
    }
    __syncthreads();

    // roffL[t] = S1[160b + t - 1]  (S1 = scan of bs0), recomputed locally
    if (tid < SPB / 16) {
        float v;
        if (tid == 0) {
            v = (b == 0) ? 0.f : (bs1prev + S2w[0]);      // full-row inner1 = bs1
        } else {
            int lr = (tid - 1) >> 4;                      // local bs1-row 0..9
            int p  = (tid - 1) & 15;
            float acc = pr[(lr * 16) * 16 + 15];          // local bs0 via row prefix
            for (int q = 1; q <= p; ++q) acc = acc + pr[(lr * 16 + q) * 16 + 15];
            int gr = 10 * b + lr;
            v = gr ? (acc + S2w[lr + 1]) : acc;           // S2w[lr+1] = S2[gr-1]
        }
        roffL[tid] = v;
    }
    __syncthreads();

    // per-sample: C = fl(prefix + roff); idx = (C - inc) % 512; lerp; amplitude
    #pragma unroll
    for (int i = 0; i < SPB / 512; ++i) {
        int tl = i * 512 + tid;
        size_t tg = base + tl;
        float C = pr[tl] + roffL[tl >> 4];
        float sub = C - increg[i];
        float idx = fmodf(sub, 512.0f);
        if (idx < 0.f) idx += 512.f;
        int li = (int)idx;
        float alpha = idx - (float)li;
        int hi = ((int)ceilf(idx)) & (WTLEN - 1);
        int fr = tl / BLKSZ;
        float wlo = mixrow[fr][li];
        float whi = mixrow[fr][hi];
        out[tg] = (wlo + alpha * (whi - wlo)) * amp[tg];
    }
}

extern "C" void kernel_launch(void* const* d_in, const int* in_sizes, int n_in,
                              void* d_out, int out_size, void* d_ws, size_t ws_size,
                              hipStream_t stream) {
    const float* pitch = (const float*)d_in[0];
    const float* amp   = (const float*)d_in[1];
    const float* wts   = (const float*)d_in[2];
    const float* att   = (const float*)d_in[3];

    int T      = in_sizes[0];        // 960000
    int frames = T / BLKSZ;          // 6000
    int nmain  = T / SPB;            // 375

    float* ws      = (float*)d_ws;
    float* wts_eff = ws;                     // 32768
    float* bs1     = ws + 32768;             // 3750 (pad 3840)
    float* bs2     = ws + 32768 + 3840;      // 235  (pad 256)
    float* S2      = ws + 32768 + 3840 + 256;// 3750
    float* out     = (float*)d_out;

    int nwts_blocks = (NWT * WTLEN + 255) / 256;       // 128
    k_leaf<<<NB2 + nwts_blocks, 256, 0, stream>>>(pitch, wts, bs1, bs2, wts_eff, T);
    k_mid <<<1, 512, 0, stream>>>(bs1, bs2, S2);
    k_main<<<nmain, 512, 0, stream>>>(pitch, amp, att, wts_eff, bs1, S2, out, frames);
}

// Round 12
// 28.528 us; speedup vs baseline: 1.3669x; 1.3669x over previous
//
#include <hip/hip_runtime.h>
#include <math.h>

#define BLKSZ 160
#define NWT   64
#define WTLEN 512
#define FPB   16      // frames per main block
#define SPB   2560    // samples per main block (16*160)

// ReduceWindowRewriter(base_length=16) level sizes for T=960000
#define NB1   3750    // T/256
#define NB1P  3760    // padded to 235*16
#define NB2   235
#define NB2P  240
#define NB3   15      // < 16 -> naive sequential top scan

// f32 increment exactly as the reference: (pitch / 16000) * 512
static __device__ __forceinline__ float inc32_of(float p) {
    return (p / 16000.0f) * 512.0f;
}

// K1: leaf levels. blocks [0,235): per-4096-sample tree -> bs1 (16 values).
//     blocks [235,363): wts_eff (rows 0..3 raw, 4..63 tanh).
__global__ __launch_bounds__(256) void k_leaf(
    const float* __restrict__ pitch, const float* __restrict__ wts,
    float* __restrict__ bs1, float* __restrict__ wts_eff, int T)
{
    int t = threadIdx.x;
    if (blockIdx.x >= NB2) {                      // wts_eff part
        int i = (blockIdx.x - NB2) * 256 + t;
        if (i < NWT * WTLEN) {
            float v = wts[i];
            if ((i >> 9) >= 4) v = tanhf(v);
            wts_eff[i] = v;
        }
        return;
    }
    __shared__ float b0[256];
    int blk = blockIdx.x;
    size_t s0 = (size_t)blk * 4096;
    int nsamp = min(4096, T - (int)s0);
    int nb0 = nsamp >> 4;                         // 256 or 96
    if (t < nb0) {                                // bs0: seq 16-chain of incs
        const float4* p4 = (const float4*)(pitch + s0 + (size_t)t * 16);
        float acc = 0.f;
        #pragma unroll
        for (int i = 0; i < 4; ++i) {
            float4 v = p4[i];
            acc = acc + inc32_of(v.x);
            acc = acc + inc32_of(v.y);
            acc = acc + inc32_of(v.z);
            acc = acc + inc32_of(v.w);
        }
        b0[t] = acc;
    }
    __syncthreads();
    int nb1 = nb0 >> 4;                           // 16 or 6
    if (t < nb1) {                                // bs1: seq 16-chain of bs0
        float acc = b0[t * 16];
        for (int j = 1; j < 16; ++j) acc = acc + b0[t * 16 + j];
        bs1[blk * 16 + t] = acc;
    }
}

// K2: fused softmax -> upper-levels recompute -> mixrow -> prefixes -> lerp -> amp
__global__ __launch_bounds__(512) void k_main(
    const float* __restrict__ pitch, const float* __restrict__ amp,
    const float* __restrict__ att, const float* __restrict__ wts_eff,
    const float* __restrict__ bs1g, float* __restrict__ out, int frames)
{
    __shared__ float sm[FPB][NWT];          // 4 KB
    __shared__ float mixrow[FPB][WTLEN];    // 32 KB; head doubles as bs1L (3760 f)
    __shared__ float pr[SPB];               // 10 KB: inc -> within-16 prefix in place
    __shared__ float roffL[SPB / 16];       // 160
    __shared__ float bs2L[NB2P];            // zero-padded
    __shared__ float bs3L[NB3];
    __shared__ float S4L[NB3];
    __shared__ float S3w[2];
    __shared__ float S2w[11];
    __shared__ float bs1prevL;

    float* bs1L = &mixrow[0][0];            // overlay: dead before mixrow write

    int tid = threadIdx.x, lane = tid & 63, wv = tid >> 6;
    int b = blockIdx.x;
    int f0 = b * FPB;
    size_t base = (size_t)b * SPB;
    int j0 = 10 * b - 2;
    int rlo = max(j0, 0) >> 4;              // bs1-row window base for S2

    // ---- softmax: 8 waves x 2 frames (identical to R8) ----
    #pragma unroll
    for (int r = 0; r < 2; ++r) {
        int f = f0 + wv * 2 + r;
        float a = att[(size_t)lane * frames + f];
        float m = a;
        #pragma unroll
        for (int off = 32; off; off >>= 1) m = fmaxf(m, __shfl_xor(m, off, 64));
        float e = expf(a - m);
        float s = e;
        #pragma unroll
        for (int off = 32; off; off >>= 1) s += __shfl_xor(s, off, 64);
        sm[wv * 2 + r][lane] = e / s;
    }

    // ---- stage incs (regs + LDS) and load all bs1 into overlay ----
    float increg[SPB / 512];
    #pragma unroll
    for (int i = 0; i < SPB / 512; ++i) {
        increg[i] = inc32_of(pitch[base + i * 512 + tid]);
        pr[i * 512 + tid] = increg[i];
    }
    for (int i = tid; i < NB1P; i += 512)
        bs1L[i] = (i < NB1) ? bs1g[i] : 0.f;
    __syncthreads();

    // ---- within-16 prefixes (160 thr) || bs2 chains (240 thr) ----
    if (tid < SPB / 16) {
        int bofs = tid * 16;
        float acc = pr[bofs];
        for (int j = 1; j < 16; ++j) { acc = acc + pr[bofs + j]; pr[bofs + j] = acc; }
    }
    if (tid >= 272 && tid < 272 + NB2P) {
        int t2 = tid - 272;
        float a = 0.f;
        if (t2 < NB2) {
            a = bs1L[t2 * 16];
            for (int j = 1; j < 16; ++j) a = a + bs1L[t2 * 16 + j];
        }
        bs2L[t2] = a;
    }
    __syncthreads();
    // ---- bs3: chain of 16 bs2 ----
    if (tid < NB3) {
        float a = bs2L[tid * 16];
        for (int j = 1; j < 16; ++j) a = a + bs2L[tid * 16 + j];
        bs3L[tid] = a;
    }
    __syncthreads();
    // ---- S4: naive sequential scan (15 < 16) ----
    if (tid == 0) {
        float a = 0.f;
        for (int i = 0; i < NB3; ++i) { a = a + bs3L[i]; S4L[i] = a; }
    }
    __syncthreads();
    // ---- the two S3 values this block needs ----
    if (tid < 2) {
        int r = rlo - 1 + tid;
        float v = 0.f;
        if (r >= 0 && r < NB2) {
            int g = r >> 4, p = r & 15;
            float a = bs2L[g * 16];
            for (int k = 1; k <= p; ++k) a = a + bs2L[g * 16 + k];
            v = g ? (a + S4L[g - 1]) : a;
        }
        S3w[tid] = v;
    }
    if (tid == 2) bs1prevL = (b > 0) ? bs1L[10 * b - 1] : 0.f;
    __syncthreads();
    // ---- the 11 S2 values: S2[j] = inner2(j) + S3[(j>>4)-1] ----
    if (tid < 11) {
        int j = j0 + tid;
        float v = 0.f;
        if (j >= 0) {
            int r = j >> 4, p = j & 15;
            float a = bs1L[r * 16];
            for (int q = 1; q <= p; ++q) a = a + bs1L[r * 16 + q];
            v = r ? (a + S3w[r - rlo]) : a;
        }
        S2w[tid] = v;
    }
    __syncthreads();    // bs1L dead from here on

    // ---- roffL (160 thr) || mixrow (all threads; overwrites overlay) ----
    if (tid < SPB / 16) {
        float v;
        if (tid == 0) {
            v = (b == 0) ? 0.f : (bs1prevL + S2w[0]);
        } else {
            int lr = (tid - 1) >> 4;
            int p  = (tid - 1) & 15;
            float acc = pr[(lr * 16) * 16 + 15];
            for (int q = 1; q <= p; ++q) acc = acc + pr[(lr * 16 + q) * 16 + 15];
            int gr = 10 * b + lr;
            v = gr ? (acc + S2w[lr + 1]) : acc;
        }
        roffL[tid] = v;
    }
    {
        float acc[FPB];
        #pragma unroll
        for (int k = 0; k < FPB; ++k) acc[k] = 0.f;
        for (int w = 0; w < NWT; ++w) {
            float v = wts_eff[w * WTLEN + tid];
            #pragma unroll
            for (int k = 0; k < FPB; ++k) acc[k] += sm[k][w] * v;   // LDS broadcast
        }
        #pragma unroll
        for (int k = 0; k < FPB; ++k) mixrow[k][tid] = acc[k];
    }
    __syncthreads();

    // ---- per-sample: C = fl(prefix + roff); idx = (C-inc) % 512; lerp; amp ----
    #pragma unroll
    for (int i = 0; i < SPB / 512; ++i) {
        int tl = i * 512 + tid;
        size_t tg = base + tl;
        float C = pr[tl] + roffL[tl >> 4];
        float sub = C - increg[i];
        float idx = fmodf(sub, 512.0f);
        if (idx < 0.f) idx += 512.f;
        int li = (int)idx;
        float alpha = idx - (float)li;
        int hi = ((int)ceilf(idx)) & (WTLEN - 1);
        int fr = tl / BLKSZ;
        float wlo = mixrow[fr][li];
        float whi = mixrow[fr][hi];
        out[tg] = (wlo + alpha * (whi - wlo)) * amp[tg];
    }
}

extern "C" void kernel_launch(void* const* d_in, const int* in_sizes, int n_in,
                              void* d_out, int out_size, void* d_ws, size_t ws_size,
                              hipStream_t stream) {
    const float* pitch = (const float*)d_in[0];
    const float* amp   = (const float*)d_in[1];
    const float* wts   = (const float*)d_in[2];
    const float* att   = (const float*)d_in[3];

    int T      = in_sizes[0];        // 960000
    int frames = T / BLKSZ;          // 6000
    int nmain  = T / SPB;            // 375

    float* ws      = (float*)d_ws;
    float* wts_eff = ws;             // 32768 floats
    float* bs1     = ws + 32768;     // 3750 floats
    float* out     = (float*)d_out;

    int nwts_blocks = (NWT * WTLEN + 255) / 256;       // 128
    k_leaf<<<NB2 + nwts_blocks, 256, 0, stream>>>(pitch, wts, bs1, wts_eff, T);
    k_main<<<nmain, 512, 0, stream>>>(pitch, amp, att, wts_eff, bs1, out, frames);
}

// Round 13
// 26.584 us; speedup vs baseline: 1.4669x; 1.0731x over previous
//
#include <hip/hip_runtime.h>
#include <math.h>

#define BLKSZ 160
#define NWT   64
#define WTLEN 512
#define FPB   16      // frames per main block
#define SPB   2560    // samples per main block (16*160)
#define SMP   20      // smT row pitch (floats): 16B-aligned, breaks 2^k bank stride

// ReduceWindowRewriter(base_length=16) level sizes for T=960000
#define NB1   3750    // T/256
#define NB1P  3760    // padded to 235*16
#define NB2   235
#define NB2P  240
#define NB3   15      // < 16 -> naive sequential top scan

// f32 increment exactly as the reference: (pitch / 16000) * 512
static __device__ __forceinline__ float inc32_of(float p) {
    return (p / 16000.0f) * 512.0f;
}

// K1: leaf levels. blocks [0,235): per-4096-sample tree -> bs1 (16 values).
//     blocks [235,363): wts_eff (rows 0..3 raw, 4..63 tanh).
__global__ __launch_bounds__(256) void k_leaf(
    const float* __restrict__ pitch, const float* __restrict__ wts,
    float* __restrict__ bs1, float* __restrict__ wts_eff, int T)
{
    int t = threadIdx.x;
    if (blockIdx.x >= NB2) {                      // wts_eff part
        int i = (blockIdx.x - NB2) * 256 + t;
        if (i < NWT * WTLEN) {
            float v = wts[i];
            if ((i >> 9) >= 4) v = tanhf(v);
            wts_eff[i] = v;
        }
        return;
    }
    __shared__ float b0[256];
    int blk = blockIdx.x;
    size_t s0 = (size_t)blk * 4096;
    int nsamp = min(4096, T - (int)s0);
    int nb0 = nsamp >> 4;                         // 256 or 96
    if (t < nb0) {                                // bs0: seq 16-chain of incs
        const float4* p4 = (const float4*)(pitch + s0 + (size_t)t * 16);
        float acc = 0.f;
        #pragma unroll
        for (int i = 0; i < 4; ++i) {
            float4 v = p4[i];
            acc = acc + inc32_of(v.x);
            acc = acc + inc32_of(v.y);
            acc = acc + inc32_of(v.z);
            acc = acc + inc32_of(v.w);
        }
        b0[t] = acc;
    }
    __syncthreads();
    int nb1 = nb0 >> 4;                           // 16 or 6
    if (t < nb1) {                                // bs1: seq 16-chain of bs0
        float acc = b0[t * 16];
        for (int j = 1; j < 16; ++j) acc = acc + b0[t * 16 + j];
        bs1[blk * 16 + t] = acc;
    }
}

// K2: fused softmax -> upper-levels recompute -> mixrow (b128 weights) -> lerp -> amp
__global__ __launch_bounds__(512) void k_main(
    const float* __restrict__ pitch, const float* __restrict__ amp,
    const float* __restrict__ att, const float* __restrict__ wts_eff,
    const float* __restrict__ bs1g, float* __restrict__ out, int frames)
{
    __shared__ float smT[NWT][SMP];         // 5 KB: transposed weights, padded rows
    __shared__ float mixrow[FPB][WTLEN];    // 32 KB; head doubles as bs1L (3760 f)
    __shared__ float pr[SPB];               // 10 KB: inc -> within-16 prefix in place
    __shared__ float roffL[SPB / 16];       // 160
    __shared__ float bs2L[NB2P];            // zero-padded
    __shared__ float bs3L[NB3];
    __shared__ float S4L[NB3];
    __shared__ float S3w[2];
    __shared__ float S2w[11];
    __shared__ float bs1prevL;

    float* bs1L = &mixrow[0][0];            // overlay: dead before mixrow write

    int tid = threadIdx.x, lane = tid & 63, wv = tid >> 6;
    int b = blockIdx.x;
    int f0 = b * FPB;
    size_t base = (size_t)b * SPB;
    int j0 = 10 * b - 2;
    int rlo = max(j0, 0) >> 4;              // bs1-row window base for S2

    // ---- softmax: 8 waves x 2 frames; lane = wavetable, write transposed ----
    #pragma unroll
    for (int r = 0; r < 2; ++r) {
        int f = f0 + wv * 2 + r;
        float a = att[(size_t)lane * frames + f];
        float m = a;
        #pragma unroll
        for (int off = 32; off; off >>= 1) m = fmaxf(m, __shfl_xor(m, off, 64));
        float e = expf(a - m);
        float s = e;
        #pragma unroll
        for (int off = 32; off; off >>= 1) s += __shfl_xor(s, off, 64);
        smT[lane][wv * 2 + r] = e / s;
    }

    // ---- stage incs (regs + LDS) and load all bs1 into overlay ----
    float increg[SPB / 512];
    #pragma unroll
    for (int i = 0; i < SPB / 512; ++i) {
        increg[i] = inc32_of(pitch[base + i * 512 + tid]);
        pr[i * 512 + tid] = increg[i];
    }
    for (int i = tid; i < NB1P; i += 512)
        bs1L[i] = (i < NB1) ? bs1g[i] : 0.f;
    __syncthreads();

    // ---- within-16 prefixes (160 thr) || bs2 chains (240 thr) ----
    if (tid < SPB / 16) {
        int bofs = tid * 16;
        float acc = pr[bofs];
        for (int j = 1; j < 16; ++j) { acc = acc + pr[bofs + j]; pr[bofs + j] = acc; }
    }
    if (tid >= 272 && tid < 272 + NB2P) {
        int t2 = tid - 272;
        float a = 0.f;
        if (t2 < NB2) {
            a = bs1L[t2 * 16];
            for (int j = 1; j < 16; ++j) a = a + bs1L[t2 * 16 + j];
        }
        bs2L[t2] = a;
    }
    __syncthreads();
    // ---- bs3: chain of 16 bs2 ----
    if (tid < NB3) {
        float a = bs2L[tid * 16];
        for (int j = 1; j < 16; ++j) a = a + bs2L[tid * 16 + j];
        bs3L[tid] = a;
    }
    __syncthreads();
    // ---- S4: naive sequential scan (15 < 16) ----
    if (tid == 0) {
        float a = 0.f;
        for (int i = 0; i < NB3; ++i) { a = a + bs3L[i]; S4L[i] = a; }
    }
    __syncthreads();
    // ---- the two S3 values this block needs ----
    if (tid < 2) {
        int r = rlo - 1 + tid;
        float v = 0.f;
        if (r >= 0 && r < NB2) {
            int g = r >> 4, p = r & 15;
            float a = bs2L[g * 16];
            for (int k = 1; k <= p; ++k) a = a + bs2L[g * 16 + k];
            v = g ? (a + S4L[g - 1]) : a;
        }
        S3w[tid] = v;
    }
    if (tid == 2) bs1prevL = (b > 0) ? bs1L[10 * b - 1] : 0.f;
    __syncthreads();
    // ---- the 11 S2 values: S2[j] = inner2(j) + S3[(j>>4)-1] ----
    if (tid < 11) {
        int j = j0 + tid;
        float v = 0.f;
        if (j >= 0) {
            int r = j >> 4, p = j & 15;
            float a = bs1L[r * 16];
            for (int q = 1; q <= p; ++q) a = a + bs1L[r * 16 + q];
            v = r ? (a + S3w[r - rlo]) : a;
        }
        S2w[tid] = v;
    }
    __syncthreads();    // bs1L dead from here on

    // ---- roffL (160 thr) || mixrow (all threads; overwrites overlay) ----
    if (tid < SPB / 16) {
        float v;
        if (tid == 0) {
            v = (b == 0) ? 0.f : (bs1prevL + S2w[0]);
        } else {
            int lr = (tid - 1) >> 4;
            int p  = (tid - 1) & 15;
            float acc = pr[(lr * 16) * 16 + 15];
            for (int q = 1; q <= p; ++q) acc = acc + pr[(lr * 16 + q) * 16 + 15];
            int gr = 10 * b + lr;
            v = gr ? (acc + S2w[lr + 1]) : acc;
        }
        roffL[tid] = v;
    }
    {
        float acc[FPB];
        #pragma unroll
        for (int k = 0; k < FPB; ++k) acc[k] = 0.f;
        for (int w = 0; w < NWT; ++w) {
            float v = wts_eff[w * WTLEN + tid];
            // 4 broadcast ds_read_b128: 16 weights of frame 0..15 for table w
            float4 s0 = *(const float4*)&smT[w][0];
            float4 s1 = *(const float4*)&smT[w][4];
            float4 s2 = *(const float4*)&smT[w][8];
            float4 s3 = *(const float4*)&smT[w][12];
            acc[0]  += s0.x * v;  acc[1]  += s0.y * v;
            acc[2]  += s0.z * v;  acc[3]  += s0.w * v;
            acc[4]  += s1.x * v;  acc[5]  += s1.y * v;
            acc[6]  += s1.z * v;  acc[7]  += s1.w * v;
            acc[8]  += s2.x * v;  acc[9]  += s2.y * v;
            acc[10] += s2.z * v;  acc[11] += s2.w * v;
            acc[12] += s3.x * v;  acc[13] += s3.y * v;
            acc[14] += s3.z * v;  acc[15] += s3.w * v;
        }
        #pragma unroll
        for (int k = 0; k < FPB; ++k) mixrow[k][tid] = acc[k];
    }
    __syncthreads();

    // ---- per-sample: C = fl(prefix + roff); idx = (C-inc) % 512; lerp; amp ----
    #pragma unroll
    for (int i = 0; i < SPB / 512; ++i) {
        int tl = i * 512 + tid;
        size_t tg = base + tl;
        float C = pr[tl] + roffL[tl >> 4];
        float sub = C - increg[i];
        float idx = fmodf(sub, 512.0f);
        if (idx < 0.f) idx += 512.f;
        int li = (int)idx;
        float alpha = idx - (float)li;
        int hi = ((int)ceilf(idx)) & (WTLEN - 1);
        int fr = tl / BLKSZ;
        float wlo = mixrow[fr][li];
        float whi = mixrow[fr][hi];
        out[tg] = (wlo + alpha * (whi - wlo)) * amp[tg];
    }
}

extern "C" void kernel_launch(void* const* d_in, const int* in_sizes, int n_in,
                              void* d_out, int out_size, void* d_ws, size_t ws_size,
                              hipStream_t stream) {
    const float* pitch = (const float*)d_in[0];
    const float* amp   = (const float*)d_in[1];
    const float* wts   = (const float*)d_in[2];
    const float* att   = (const float*)d_in[3];

    int T      = in_sizes[0];        // 960000
    int frames = T / BLKSZ;          // 6000
    int nmain  = T / SPB;            // 375

    float* ws      = (float*)d_ws;
    float* wts_eff = ws;             // 32768 floats
    float* bs1     = ws + 32768;     // 3750 floats
    float* out     = (float*)d_out;

    int nwts_blocks = (NWT * WTLEN + 255) / 256;       // 128
    k_leaf<<<NB2 + nwts_blocks, 256, 0, stream>>>(pitch, wts, bs1, wts_eff, T);
    k_main<<<nmain, 512, 0, stream>>>(pitch, amp, att, wts_eff, bs1, out, frames);
}

// Round 14
// 25.571 us; speedup vs baseline: 1.5249x; 1.0396x over previous
//
#include <hip/hip_runtime.h>
#include <math.h>

#define BLKSZ 160
#define NWT   64
#define WTLEN 512
#define FPB   24      // frames per main block
#define SPB   3840    // samples per main block (24*160)
#define NTHR  768     // 12 waves
#define SMP   28      // smT row pitch (floats), 16B-aligned

// ReduceWindowRewriter(base_length=16) level sizes for T=960000
#define NB1   3750    // T/256
#define NB1P  3760    // padded to 235*16
#define NB2   235
#define NB2P  240
#define NB3   15      // < 16 -> naive sequential top scan

// f32 increment exactly as the reference: (pitch / 16000) * 512
static __device__ __forceinline__ float inc32_of(float p) {
    return (p / 16000.0f) * 512.0f;
}

// K1: leaf levels. blocks [0,235): per-4096-sample tree -> bs1 (16 values).
//     blocks [235,363): wts_eff (rows 0..3 raw, 4..63 tanh).
__global__ __launch_bounds__(256) void k_leaf(
    const float* __restrict__ pitch, const float* __restrict__ wts,
    float* __restrict__ bs1, float* __restrict__ wts_eff, int T)
{
    int t = threadIdx.x;
    if (blockIdx.x >= NB2) {                      // wts_eff part
        int i = (blockIdx.x - NB2) * 256 + t;
        if (i < NWT * WTLEN) {
            float v = wts[i];
            if ((i >> 9) >= 4) v = tanhf(v);
            wts_eff[i] = v;
        }
        return;
    }
    __shared__ float b0[256];
    int blk = blockIdx.x;
    size_t s0 = (size_t)blk * 4096;
    int nsamp = min(4096, T - (int)s0);
    int nb0 = nsamp >> 4;                         // 256 or 96
    if (t < nb0) {                                // bs0: seq 16-chain of incs
        const float4* p4 = (const float4*)(pitch + s0 + (size_t)t * 16);
        float acc = 0.f;
        #pragma unroll
        for (int i = 0; i < 4; ++i) {
            float4 v = p4[i];
            acc = acc + inc32_of(v.x);
            acc = acc + inc32_of(v.y);
            acc = acc + inc32_of(v.z);
            acc = acc + inc32_of(v.w);
        }
        b0[t] = acc;
    }
    __syncthreads();
    int nb1 = nb0 >> 4;                           // 16 or 6
    if (t < nb1) {                                // bs1: seq 16-chain of bs0
        float acc = b0[t * 16];
        for (int j = 1; j < 16; ++j) acc = acc + b0[t * 16 + j];
        bs1[blk * 16 + t] = acc;
    }
}

// K2: fused softmax -> upper-levels recompute -> mixrow -> prefixes -> lerp -> amp
__global__ __launch_bounds__(768, 3) void k_main(
    const float* __restrict__ pitch, const float* __restrict__ amp,
    const float* __restrict__ att, const float* __restrict__ wts_eff,
    const float* __restrict__ bs1g, float* __restrict__ out, int frames)
{
    __shared__ float smT[NWT][SMP];         // 7 KB: transposed weights, padded rows
    __shared__ float mixrow[FPB][WTLEN];    // 48 KB; head doubles as bs1L (3760 f)
    __shared__ float pr[SPB];               // 15 KB: inc -> within-16 prefix in place
    __shared__ float roffL[SPB / 16];       // 240
    __shared__ float bs2L[NB2P];            // zero-padded
    __shared__ float bs3L[NB3];
    __shared__ float S4L[NB3];
    __shared__ float S3w[2];
    __shared__ float S2w[16];
    __shared__ float bs1prevL;

    float* bs1L = &mixrow[0][0];            // overlay: dead before mixrow write

    int tid = threadIdx.x, lane = tid & 63, wv = tid >> 6;   // wv in [0,12)
    int b = blockIdx.x;
    int f0 = b * FPB;
    size_t base = (size_t)b * SPB;
    int j0 = 15 * b - 2;                    // S2 window start
    int rlo = max(j0, 0) >> 4;              // bs1-row window base for S2

    // ---- softmax: 12 waves x 2 frames; lane = wavetable, write transposed ----
    #pragma unroll
    for (int r = 0; r < 2; ++r) {
        int f = f0 + wv * 2 + r;
        float a = att[(size_t)lane * frames + f];
        float m = a;
        #pragma unroll
        for (int off = 32; off; off >>= 1) m = fmaxf(m, __shfl_xor(m, off, 64));
        float e = expf(a - m);
        float s = e;
        #pragma unroll
        for (int off = 32; off; off >>= 1) s += __shfl_xor(s, off, 64);
        smT[lane][wv * 2 + r] = e / s;
    }

    // ---- stage incs (regs + LDS) and load all bs1 into overlay ----
    float increg[SPB / NTHR];
    #pragma unroll
    for (int i = 0; i < SPB / NTHR; ++i) {
        increg[i] = inc32_of(pitch[base + i * NTHR + tid]);
        pr[i * NTHR + tid] = increg[i];
    }
    for (int i = tid; i < NB1P; i += NTHR)
        bs1L[i] = (i < NB1) ? bs1g[i] : 0.f;
    __syncthreads();

    // ---- within-16 prefixes (240 thr) || bs2 chains (240 thr) ----
    if (tid < SPB / 16) {
        int bofs = tid * 16;
        float acc = pr[bofs];
        for (int j = 1; j < 16; ++j) { acc = acc + pr[bofs + j]; pr[bofs + j] = acc; }
    }
    if (tid >= 272 && tid < 272 + NB2P) {
        int t2 = tid - 272;
        float a = 0.f;
        if (t2 < NB2) {
            a = bs1L[t2 * 16];
            for (int j = 1; j < 16; ++j) a = a + bs1L[t2 * 16 + j];
        }
        bs2L[t2] = a;
    }
    __syncthreads();
    // ---- bs3: chain of 16 bs2 ----
    if (tid < NB3) {
        float a = bs2L[tid * 16];
        for (int j = 1; j < 16; ++j) a = a + bs2L[tid * 16 + j];
        bs3L[tid] = a;
    }
    __syncthreads();
    // ---- S4: naive sequential scan (15 < 16) ----
    if (tid == 0) {
        float a = 0.f;
        for (int i = 0; i < NB3; ++i) { a = a + bs3L[i]; S4L[i] = a; }
    }
    __syncthreads();
    // ---- the two S3 values this block needs ----
    if (tid < 2) {
        int r = rlo - 1 + tid;
        float v = 0.f;
        if (r >= 0 && r < NB2) {
            int g = r >> 4, p = r & 15;
            float a = bs2L[g * 16];
            for (int k = 1; k <= p; ++k) a = a + bs2L[g * 16 + k];
            v = g ? (a + S4L[g - 1]) : a;
        }
        S3w[tid] = v;
    }
    if (tid == 2) bs1prevL = (b > 0) ? bs1L[15 * b - 1] : 0.f;
    __syncthreads();
    // ---- the 16 S2 values: S2[j] = inner2(j) + S3[(j>>4)-1] ----
    if (tid < 16) {
        int j = j0 + tid;
        float v = 0.f;
        if (j >= 0) {
            int r = j >> 4, p = j & 15;
            float a = bs1L[r * 16];
            for (int q = 1; q <= p; ++q) a = a + bs1L[r * 16 + q];
            v = r ? (a + S3w[r - rlo]) : a;
        }
        S2w[tid] = v;
    }
    __syncthreads();    // bs1L dead from here on

    // ---- roffL (240 thr) || mixrow (all threads; overwrites overlay) ----
    if (tid < SPB / 16) {
        float v;
        if (tid == 0) {
            v = (b == 0) ? 0.f : (bs1prevL + S2w[0]);
        } else {
            int lr = (tid - 1) >> 4;
            int p  = (tid - 1) & 15;
            float acc = pr[(lr * 16) * 16 + 15];
            for (int q = 1; q <= p; ++q) acc = acc + pr[(lr * 16 + q) * 16 + 15];
            int gr = 15 * b + lr;
            v = gr ? (acc + S2w[lr + 1]) : acc;
        }
        roffL[tid] = v;
    }
    {
        // 1536 items = (fgroup 0..2) x (j 0..511); thread does items tid, tid+768.
        // Per item: 8 frames, 64 w-iters, same per-(w,k) ops as before -> bit-exact.
        #pragma unroll
        for (int it = 0; it < 2; ++it) {
            int item = tid + it * NTHR;
            int fg = item >> 9;             // 0..2
            int j  = item & 511;
            float acc[8];
            #pragma unroll
            for (int k = 0; k < 8; ++k) acc[k] = 0.f;
            for (int w = 0; w < NWT; ++w) {
                float v = wts_eff[w * WTLEN + j];
                float4 s0 = *(const float4*)&smT[w][fg * 8];
                float4 s1 = *(const float4*)&smT[w][fg * 8 + 4];
                acc[0] += s0.x * v;  acc[1] += s0.y * v;
                acc[2] += s0.z * v;  acc[3] += s0.w * v;
                acc[4] += s1.x * v;  acc[5] += s1.y * v;
                acc[6] += s1.z * v;  acc[7] += s1.w * v;
            }
            #pragma unroll
            for (int k = 0; k < 8; ++k) mixrow[fg * 8 + k][j] = acc[k];
        }
    }
    __syncthreads();

    // ---- per-sample: C = fl(prefix + roff); idx = (C-inc) % 512; lerp; amp ----
    #pragma unroll
    for (int i = 0; i < SPB / NTHR; ++i) {
        int tl = i * NTHR + tid;
        size_t tg = base + tl;
        float C = pr[tl] + roffL[tl >> 4];
        float sub = C - increg[i];
        float idx = fmodf(sub, 512.0f);
        if (idx < 0.f) idx += 512.f;
        int li = (int)idx;
        float alpha = idx - (float)li;
        int hi = ((int)ceilf(idx)) & (WTLEN - 1);
        int fr = tl / BLKSZ;
        float wlo = mixrow[fr][li];
        float whi = mixrow[fr][hi];
        out[tg] = (wlo + alpha * (whi - wlo)) * amp[tg];
    }
}

extern "C" void kernel_launch(void* const* d_in, const int* in_sizes, int n_in,
                              void* d_out, int out_size, void* d_ws, size_t ws_size,
                              hipStream_t stream) {
    const float* pitch = (const float*)d_in[0];
    const float* amp   = (const float*)d_in[1];
    const float* wts   = (const float*)d_in[2];
    const float* att   = (const float*)d_in[3];

    int T      = in_sizes[0];        // 960000
    int frames = T / BLKSZ;          // 6000
    int nmain  = T / SPB;            // 250

    float* ws      = (float*)d_ws;
    float* wts_eff = ws;             // 32768 floats
    float* bs1     = ws + 32768;     // 3750 floats
    float* out     = (float*)d_out;

    int nwts_blocks = (NWT * WTLEN + 255) / 256;       // 128
    k_leaf<<<NB2 + nwts_blocks, 256, 0, stream>>>(pitch, wts, bs1, wts_eff, T);
    k_main<<<nmain, 768, 0, stream>>>(pitch, amp, att, wts_eff, bs1, out, frames);
}